// Round 2
// 158.874 us; speedup vs baseline: 1.2996x; 1.2996x over previous
//
#include <hip/hip_runtime.h>

// Problem constants (complete bipartite proxy<->sample + self-loops)
#define PP 100    // proxies
#define NS 1024   // samples
#define NN 1124   // total nodes
#define DD 512    // feature dim
#define CC 100    // fc out dim
#define NTHR 256

typedef _Float16 f16;
typedef _Float16 f16x8 __attribute__((ext_vector_type(8)));
typedef float    f32x4 __attribute__((ext_vector_type(4)));

__device__ __forceinline__ float lk(float v) { return v > 0.f ? v : 0.2f * v; }
__device__ __forceinline__ f16 hif(float v) { return (f16)v; }
__device__ __forceinline__ f16 lof(float v) { return (f16)(v - (float)((f16)v)); }

// =================== MFMA split-f16 GEMM core =============================
// acc[2][2] += A[row0.., K] @ B  where A given as (Ah,Al) row-major [*,K],
// B given TRANSPOSED as (Bth,Btl) row-major [*,K] (row = output col).
// Block tile 64x64, 4 waves of 32x32 (2x2 frags 16x16), BK=32, K % 32 == 0.
// C = Ah*Bh + Al*Bh + Ah*Bl  (split-f16, fp32 accumulate; al*bl dropped).
// lds: f16[4*64*40] (rows padded to 40 halves -> 16B-aligned, spread banks).
__device__ __forceinline__ void mgemm_core(
    const f16* __restrict__ Ah, const f16* __restrict__ Al,
    const f16* __restrict__ Bth, const f16* __restrict__ Btl,
    int K, int row0, int col0, f16* __restrict__ lds, f32x4 acc[2][2])
{
  const int t = threadIdx.x;
  const int lane = t & 63, w = t >> 6;
  const int wr = w >> 1, wc = w & 1;
  f16* Ash = lds;
  f16* Asl = lds + 2560;
  f16* Bsh = lds + 5120;
  f16* Bsl = lds + 7680;
  const int srow = t >> 2, su = t & 3;                 // staging: row, 8-half unit
  const size_t aoff = (size_t)(row0 + srow) * K + su * 8;
  const size_t boff = (size_t)(col0 + srow) * K + su * 8;
  const int lw = srow * 40 + su * 8;
  f32x4 pa0 = *(const f32x4*)(Ah + aoff);
  f32x4 pa1 = *(const f32x4*)(Al + aoff);
  f32x4 pb0 = *(const f32x4*)(Bth + boff);
  f32x4 pb1 = *(const f32x4*)(Btl + boff);
  const int fra = wr * 32 + (lane & 15);               // A frag row (local)
  const int frb = wc * 32 + (lane & 15);               // B frag col (local)
  const int fu  = (lane >> 4) * 8;                     // k offset within BK
  for (int kt = 32; kt <= K; kt += 32) {
    *(f32x4*)(Ash + lw) = pa0;
    *(f32x4*)(Asl + lw) = pa1;
    *(f32x4*)(Bsh + lw) = pb0;
    *(f32x4*)(Bsl + lw) = pb1;
    __syncthreads();
    if (kt < K) {                                      // prefetch next tile
      pa0 = *(const f32x4*)(Ah + aoff + kt);
      pa1 = *(const f32x4*)(Al + aoff + kt);
      pb0 = *(const f32x4*)(Bth + boff + kt);
      pb1 = *(const f32x4*)(Btl + boff + kt);
    }
    f16x8 ah[2], al[2], bh[2], bl[2];
#pragma unroll
    for (int m = 0; m < 2; ++m) {
      ah[m] = *(const f16x8*)(Ash + (fra + m * 16) * 40 + fu);
      al[m] = *(const f16x8*)(Asl + (fra + m * 16) * 40 + fu);
    }
#pragma unroll
    for (int n = 0; n < 2; ++n) {
      bh[n] = *(const f16x8*)(Bsh + (frb + n * 16) * 40 + fu);
      bl[n] = *(const f16x8*)(Bsl + (frb + n * 16) * 40 + fu);
    }
#pragma unroll
    for (int m = 0; m < 2; ++m)
#pragma unroll
      for (int n = 0; n < 2; ++n) {
        acc[m][n] = __builtin_amdgcn_mfma_f32_16x16x32_f16(ah[m], bh[n], acc[m][n], 0, 0, 0);
        acc[m][n] = __builtin_amdgcn_mfma_f32_16x16x32_f16(al[m], bh[n], acc[m][n], 0, 0, 0);
        acc[m][n] = __builtin_amdgcn_mfma_f32_16x16x32_f16(ah[m], bl[n], acc[m][n], 0, 0, 0);
      }
    __syncthreads();
  }
}

// C/D frag mapping (HW-verified): col = lane&15, row = (lane>>4)*4 + q.

// ======== 64x64 transpose+split tile (fp32 in -> f16 hi/lo transposed) =====
__device__ __forceinline__ void cvt_tile(
    const float* __restrict__ in, int R, int Cin,
    f16* __restrict__ oh, f16* __restrict__ ol, int ldo,
    int ti, int tj, f16 (*th)[72], f16 (*tl)[72])
{
  const int t = threadIdx.x;
#pragma unroll
  for (int p = 0; p < 4; ++p) {
    const int f = t + p * 256;
    const int i = f >> 4, j4 = (f & 15) * 4;
    const int gi = ti * 64 + i, gj = tj * 64 + j4;
    float4 v = make_float4(0.f, 0.f, 0.f, 0.f);
    if (gi < R && gj + 3 < Cin) v = *(const float4*)(in + (size_t)gi * Cin + gj);
    th[i][j4 + 0] = hif(v.x); tl[i][j4 + 0] = lof(v.x);
    th[i][j4 + 1] = hif(v.y); tl[i][j4 + 1] = lof(v.y);
    th[i][j4 + 2] = hif(v.z); tl[i][j4 + 2] = lof(v.z);
    th[i][j4 + 3] = hif(v.w); tl[i][j4 + 3] = lof(v.w);
  }
  __syncthreads();
#pragma unroll
  for (int p = 0; p < 2; ++p) {
    const int f = t + p * 256;
    const int j = f >> 3, i8 = (f & 7) * 8;
    f16x8 vh, vl;
#pragma unroll
    for (int e = 0; e < 8; ++e) { vh[e] = th[i8 + e][j]; vl[e] = tl[i8 + e][j]; }
    const size_t o = (size_t)(tj * 64 + j) * ldo + ti * 64 + i8;
    *(f16x8*)(oh + o) = vh;
    *(f16x8*)(ol + o) = vl;
  }
}

// ===== prep: transpose+split x, prox, W1, W2, fcw  +  matvec (v = W@a) =====
__global__ __launch_bounds__(NTHR) void prep_k(
    const float* __restrict__ x, const float* __restrict__ prox,
    const float* __restrict__ W1, const float* __restrict__ W2,
    const float* __restrict__ fcw,
    const float* __restrict__ as1, const float* __restrict__ ad1,
    const float* __restrict__ as2, const float* __restrict__ ad2,
    f16* xth, f16* xtl, f16* pth, f16* ptl,
    f16* W1th, f16* W1tl, f16* W2th, f16* W2tl, f16* fwth, f16* fwtl,
    float* v1s, float* v1d, float* v2s, float* v2d)
{
  __shared__ f16 th[64][72];
  __shared__ f16 tl[64][72];
  const int b = blockIdx.x;
  if (b < 64) {
    cvt_tile(W1, 512, 512, W1th, W1tl, 512, b >> 3, b & 7, th, tl);
  } else if (b < 128) {
    cvt_tile(W2, 512, 512, W2th, W2tl, 512, (b - 64) >> 3, (b - 64) & 7, th, tl);
  } else if (b < 256) {
    cvt_tile(x, NS, 512, xth, xtl, NS, (b - 128) >> 3, (b - 128) & 7, th, tl);
  } else if (b < 272) {
    // prox_t: k-pad rows 100..127 zero-filled via row guard (meets zero A cols)
    cvt_tile(prox, PP, 512, pth, ptl, 128, (b - 256) >> 3, (b - 256) & 7, th, tl);
  } else if (b < 288) {
    cvt_tile(fcw, 512, CC, fwth, fwtl, 512, (b - 272) >> 1, (b - 272) & 1, th, tl);
  } else {
    const int wid  = (b - 288) * 4 + (threadIdx.x >> 6);   // 0..1023
    const int lane = threadIdx.x & 63;
    const int r = wid & 511;
    const bool l1 = (wid < 512);
    const float* W = l1 ? W1 : W2;
    const float4* a4 = (const float4*)(l1 ? as1 : as2);
    const float4* b4 = (const float4*)(l1 ? ad1 : ad2);
    const float4* w4 = (const float4*)(W + (size_t)r * DD);
    float4 w0 = w4[lane], w1 = w4[lane + 64];
    float4 a0 = a4[lane], a1 = a4[lane + 64];
    float4 b0 = b4[lane], b1 = b4[lane + 64];
    float s1 = w0.x * a0.x + w0.y * a0.y + w0.z * a0.z + w0.w * a0.w
             + w1.x * a1.x + w1.y * a1.y + w1.z * a1.z + w1.w * a1.w;
    float s2 = w0.x * b0.x + w0.y * b0.y + w0.z * b0.z + w0.w * b0.w
             + w1.x * b1.x + w1.y * b1.y + w1.z * b1.z + w1.w * b1.w;
#pragma unroll
    for (int off = 32; off > 0; off >>= 1) {
      s1 += __shfl_down(s1, off);
      s2 += __shfl_down(s2, off);
    }
    if (lane == 0) {
      (l1 ? v1s : v2s)[r] = s1;
      (l1 ? v1d : v2d)[r] = s2;
    }
  }
}

// ============ logits: ls[r]=row_r.vs, ld[r]=row_r.vd (one wave per row) =====
__global__ __launch_bounds__(NTHR) void lvec_k(
    const float* __restrict__ A0, const float* __restrict__ A1, int split,
    const float* __restrict__ vs, const float* __restrict__ vd,
    float* __restrict__ ls, float* __restrict__ ld)
{
  const int r    = blockIdx.x * 4 + (threadIdx.x >> 6);
  const int lane = threadIdx.x & 63;
  if (r >= NN) return;
  const float* row = (r < split) ? A0 + (size_t)r * DD : A1 + (size_t)(r - split) * DD;
  const float4* r4 = (const float4*)row;
  const float4* s4 = (const float4*)vs;
  const float4* d4 = (const float4*)vd;
  float4 v0 = r4[lane], v1 = r4[lane + 64];
  float4 a0 = s4[lane], a1 = s4[lane + 64];
  float4 b0 = d4[lane], b1 = d4[lane + 64];
  float s1 = v0.x * a0.x + v0.y * a0.y + v0.z * a0.z + v0.w * a0.w
           + v1.x * a1.x + v1.y * a1.y + v1.z * a1.z + v1.w * a1.w;
  float s2 = v0.x * b0.x + v0.y * b0.y + v0.z * b0.z + v0.w * b0.w
           + v1.x * b1.x + v1.y * b1.y + v1.z * b1.z + v1.w * b1.w;
#pragma unroll
  for (int off = 32; off > 0; off >>= 1) {
    s1 += __shfl_down(s1, off);
    s2 += __shfl_down(s2, off);
  }
  if (lane == 0) { ls[r] = s1; ld[r] = s2; }
}

// ============ softmax weights (unnormalized exp) -> split-f16 ===============
// grid: [0,256) sample dsts (wave each); [256,256+NPB) proxy dsts (block each,
// i >= PP rows just zero-fill the k-pad of Ep).
__global__ __launch_bounds__(NTHR) void alpha_k(
    const float* __restrict__ ls, const float* __restrict__ ld,
    f16* __restrict__ Esh, f16* __restrict__ Esl,
    float* __restrict__ esS, float* __restrict__ izS,
    f16* __restrict__ Eph, f16* __restrict__ Epl,
    float* __restrict__ esP, float* __restrict__ izP)
{
  const int t = threadIdx.x;
  if (blockIdx.x < 256) {
    const int lane = t & 63;
    const int i = blockIdx.x * 4 + (t >> 6);     // sample dst
    const float ldi = ld[PP + i];
    float e0 = lk(ls[lane] + ldi);               // lane < 100 always
    float e1 = (lane < PP - 64) ? lk(ls[lane + 64] + ldi) : -1e30f;
    const float eself = lk(ls[PP + i] + ldi);
    float m = fmaxf(fmaxf(e0, e1), eself);
#pragma unroll
    for (int off = 1; off < 64; off <<= 1) m = fmaxf(m, __shfl_xor(m, off));
    float x0 = __expf(e0 - m);
    float x1 = (lane < PP - 64) ? __expf(e1 - m) : 0.f;
    float z = x0 + x1;
#pragma unroll
    for (int off = 1; off < 64; off <<= 1) z += __shfl_xor(z, off);
    Esh[(size_t)i * 128 + lane]      = hif(x0);
    Esl[(size_t)i * 128 + lane]      = lof(x0);
    Esh[(size_t)i * 128 + 64 + lane] = hif(x1);
    Esl[(size_t)i * 128 + 64 + lane] = lof(x1);
    if (lane == 0) {
      float xs = __expf(eself - m);
      esS[i] = xs;
      izS[i] = 1.f / (z + xs);
    }
  } else {
    const int i = blockIdx.x - 256;              // proxy dst (or k-pad row)
    if (i >= PP) {                               // zero-fill pad rows 100..127
#pragma unroll
      for (int q = 0; q < 4; ++q) {
        Eph[(size_t)i * NS + t + q * 256] = (f16)0.f;
        Epl[(size_t)i * NS + t + q * 256] = (f16)0.f;
      }
      return;
    }
    __shared__ float red[4];
    const float ldi = ld[i];
    const float eself = lk(ls[i] + ldi);
    float e[4];
#pragma unroll
    for (int q = 0; q < 4; ++q) e[q] = lk(ls[PP + t + q * 256] + ldi);
    float m = fmaxf(fmaxf(fmaxf(e[0], e[1]), fmaxf(e[2], e[3])), eself);
#pragma unroll
    for (int off = 1; off < 64; off <<= 1) m = fmaxf(m, __shfl_xor(m, off));
    if ((t & 63) == 0) red[t >> 6] = m;
    __syncthreads();
    m = fmaxf(fmaxf(red[0], red[1]), fmaxf(red[2], red[3]));
    __syncthreads();
    float xq[4], z = 0.f;
#pragma unroll
    for (int q = 0; q < 4; ++q) { xq[q] = __expf(e[q] - m); z += xq[q]; }
#pragma unroll
    for (int off = 1; off < 64; off <<= 1) z += __shfl_xor(z, off);
    if ((t & 63) == 0) red[t >> 6] = z;
    __syncthreads();
#pragma unroll
    for (int q = 0; q < 4; ++q) {
      Eph[(size_t)i * NS + t + q * 256] = hif(xq[q]);
      Epl[(size_t)i * NS + t + q * 256] = lof(xq[q]);
    }
    if (t == 0) {
      float xs = __expf(eself - m);
      esP[i] = xs;
      izP[i] = 1.f / (red[0] + red[1] + red[2] + red[3] + xs);
    }
  }
}

// ===== layer-1 aggregation: blocks [0,128) samples, [128,144) proxies ======
__global__ __launch_bounds__(NTHR) void agg1_k(
    const f16* __restrict__ Es1h, const f16* __restrict__ Es1l,
    const f16* __restrict__ pth,  const f16* __restrict__ ptl,
    const f16* __restrict__ Eph,  const f16* __restrict__ Epl,
    const f16* __restrict__ xth,  const f16* __restrict__ xtl,
    const float* __restrict__ x, const float* __restrict__ prox,
    const float* __restrict__ esS, const float* __restrict__ izS,
    const float* __restrict__ esP, const float* __restrict__ izP,
    f16* __restrict__ M1h, f16* __restrict__ M1l)
{
  __shared__ __align__(16) f16 lds[10240];
  f32x4 acc[2][2] = {};
  const int t = threadIdx.x, lane = t & 63, w = t >> 6, wr = w >> 1, wc = w & 1;
  const int b = blockIdx.x;
  if (b < 128) {
    // M1_samp[1024,512] = Es1[1024,128] @ prox(pad 128), epi self = x
    const int row0 = (b >> 3) * 64, col0 = (b & 7) * 64;
    mgemm_core(Es1h, Es1l, pth, ptl, 128, row0, col0, lds, acc);
#pragma unroll
    for (int m = 0; m < 2; ++m)
#pragma unroll
      for (int q = 0; q < 4; ++q) {
        const int r = row0 + wr * 32 + m * 16 + (lane >> 4) * 4 + q;
        const float e = esS[r], z = izS[r];
#pragma unroll
        for (int n = 0; n < 2; ++n) {
          const int c = col0 + wc * 32 + n * 16 + (lane & 15);
          const float v = (acc[m][n][q] + e * x[(size_t)r * DD + c]) * z;
          const size_t o = (size_t)(PP + r) * DD + c;
          M1h[o] = hif(v); M1l[o] = lof(v);
        }
      }
  } else {
    // M1_prox[100,512] = Ep[100(pad128),1024] @ x, epi self = prox
    const int b2 = b - 128;
    const int row0 = (b2 >> 3) * 64, col0 = (b2 & 7) * 64;
    mgemm_core(Eph, Epl, xth, xtl, NS, row0, col0, lds, acc);
#pragma unroll
    for (int m = 0; m < 2; ++m)
#pragma unroll
      for (int q = 0; q < 4; ++q) {
        const int r = row0 + wr * 32 + m * 16 + (lane >> 4) * 4 + q;
        if (r < PP) {
          const float e = esP[r], z = izP[r];
#pragma unroll
          for (int n = 0; n < 2; ++n) {
            const int c = col0 + wc * 32 + n * 16 + (lane & 15);
            const float v = (acc[m][n][q] + e * prox[(size_t)r * DD + c]) * z;
            const size_t o = (size_t)r * DD + c;
            M1h[o] = hif(v); M1l[o] = lof(v);
          }
        }
      }
  }
}

// ===== h1 = relu(M1@W1 + b1); also emit split-transposed proxy rows ========
__global__ __launch_bounds__(NTHR) void h1_k(
    const f16* __restrict__ M1h, const f16* __restrict__ M1l,
    const f16* __restrict__ W1th, const f16* __restrict__ W1tl,
    const float* __restrict__ b1, float* __restrict__ h1,
    f16* __restrict__ h1pth, f16* __restrict__ h1ptl)
{
  __shared__ __align__(16) f16 lds[10240];
  f32x4 acc[2][2] = {};
  const int t = threadIdx.x, lane = t & 63, w = t >> 6, wr = w >> 1, wc = w & 1;
  const int b = blockIdx.x;
  const int row0 = (b >> 3) * 64, col0 = (b & 7) * 64;
  mgemm_core(M1h, M1l, W1th, W1tl, DD, row0, col0, lds, acc);
#pragma unroll
  for (int m = 0; m < 2; ++m)
#pragma unroll
    for (int q = 0; q < 4; ++q) {
      const int r = row0 + wr * 32 + m * 16 + (lane >> 4) * 4 + q;
      if (r >= NN) continue;
#pragma unroll
      for (int n = 0; n < 2; ++n) {
        const int c = col0 + wc * 32 + n * 16 + (lane & 15);
        const float v = fmaxf(acc[m][n][q] + b1[c], 0.f);
        h1[(size_t)r * DD + c] = v;
        if (r < 128) {                       // B of agg2: zero-fill k-pad rows
          const size_t o = (size_t)c * 128 + r;
          f16 hh = (f16)0.f, ll = (f16)0.f;
          if (r < PP) { hh = hif(v); ll = lof(v); }
          h1pth[o] = hh; h1ptl[o] = ll;
        }
      }
    }
}

// ===== layer-2 aggregation (sample dsts only) ==============================
__global__ __launch_bounds__(NTHR) void agg2_k(
    const f16* __restrict__ Es2h, const f16* __restrict__ Es2l,
    const f16* __restrict__ h1pth, const f16* __restrict__ h1ptl,
    const float* __restrict__ h1,
    const float* __restrict__ esS, const float* __restrict__ izS,
    f16* __restrict__ M2h, f16* __restrict__ M2l)
{
  __shared__ __align__(16) f16 lds[10240];
  f32x4 acc[2][2] = {};
  const int t = threadIdx.x, lane = t & 63, w = t >> 6, wr = w >> 1, wc = w & 1;
  const int b = blockIdx.x;
  const int row0 = (b >> 3) * 64, col0 = (b & 7) * 64;
  mgemm_core(Es2h, Es2l, h1pth, h1ptl, 128, row0, col0, lds, acc);
#pragma unroll
  for (int m = 0; m < 2; ++m)
#pragma unroll
    for (int q = 0; q < 4; ++q) {
      const int r = row0 + wr * 32 + m * 16 + (lane >> 4) * 4 + q;
      const float e = esS[r], z = izS[r];
#pragma unroll
      for (int n = 0; n < 2; ++n) {
        const int c = col0 + wc * 32 + n * 16 + (lane & 15);
        const float v = (acc[m][n][q] + e * h1[(size_t)(PP + r) * DD + c]) * z;
        const size_t o = (size_t)r * DD + c;
        M2h[o] = hif(v); M2l[o] = lof(v);
      }
    }
}

// ===== h2 = relu(M2@W2 + b2) -> d_out (fp32) + split for fc ================
__global__ __launch_bounds__(NTHR) void h2_k(
    const f16* __restrict__ M2h, const f16* __restrict__ M2l,
    const f16* __restrict__ W2th, const f16* __restrict__ W2tl,
    const float* __restrict__ b2, float* __restrict__ h2s,
    f16* __restrict__ h2h, f16* __restrict__ h2l)
{
  __shared__ __align__(16) f16 lds[10240];
  f32x4 acc[2][2] = {};
  const int t = threadIdx.x, lane = t & 63, w = t >> 6, wr = w >> 1, wc = w & 1;
  const int b = blockIdx.x;
  const int row0 = (b >> 3) * 64, col0 = (b & 7) * 64;
  mgemm_core(M2h, M2l, W2th, W2tl, DD, row0, col0, lds, acc);
#pragma unroll
  for (int m = 0; m < 2; ++m)
#pragma unroll
    for (int q = 0; q < 4; ++q) {
      const int r = row0 + wr * 32 + m * 16 + (lane >> 4) * 4 + q;
#pragma unroll
      for (int n = 0; n < 2; ++n) {
        const int c = col0 + wc * 32 + n * 16 + (lane & 15);
        const float v = fmaxf(acc[m][n][q] + b2[c], 0.f);
        const size_t o = (size_t)r * DD + c;
        h2s[o] = v;
        h2h[o] = hif(v); h2l[o] = lof(v);
      }
    }
}

// ===== preds = h2 @ fcw + fcb ==============================================
__global__ __launch_bounds__(NTHR) void fc_k(
    const f16* __restrict__ h2h, const f16* __restrict__ h2l,
    const f16* __restrict__ fwth, const f16* __restrict__ fwtl,
    const float* __restrict__ fcb, float* __restrict__ out)
{
  __shared__ __align__(16) f16 lds[10240];
  f32x4 acc[2][2] = {};
  const int t = threadIdx.x, lane = t & 63, w = t >> 6, wr = w >> 1, wc = w & 1;
  const int b = blockIdx.x;
  const int row0 = (b >> 1) * 64, col0 = (b & 1) * 64;
  mgemm_core(h2h, h2l, fwth, fwtl, DD, row0, col0, lds, acc);
#pragma unroll
  for (int m = 0; m < 2; ++m)
#pragma unroll
    for (int q = 0; q < 4; ++q) {
      const int r = row0 + wr * 32 + m * 16 + (lane >> 4) * 4 + q;
#pragma unroll
      for (int n = 0; n < 2; ++n) {
        const int c = col0 + wc * 32 + n * 16 + (lane & 15);
        if (c < CC) out[(size_t)r * CC + c] = acc[m][n][q] + fcb[c];
      }
    }
}

extern "C" void kernel_launch(void* const* d_in, const int* in_sizes, int n_in,
                              void* d_out, int out_size, void* d_ws, size_t ws_size,
                              hipStream_t stream)
{
  const float* x    = (const float*)d_in[0];
  const float* prox = (const float*)d_in[1];
  const float* W1   = (const float*)d_in[2];
  const float* as1  = (const float*)d_in[3];
  const float* ad1  = (const float*)d_in[4];
  const float* b1   = (const float*)d_in[5];
  const float* W2   = (const float*)d_in[6];
  const float* as2  = (const float*)d_in[7];
  const float* ad2  = (const float*)d_in[8];
  const float* b2   = (const float*)d_in[9];
  const float* fcw  = (const float*)d_in[10];
  const float* fcb  = (const float*)d_in[11];
  float* out = (float*)d_out;

  // fp32 workspace
  float* F = (float*)d_ws;
  float* h1   = F; F += (size_t)NN * DD;
  float* ls1  = F; F += 1152;
  float* ld1  = F; F += 1152;
  float* ls2  = F; F += 1152;
  float* ld2  = F; F += 1152;
  float* v1s  = F; F += DD;
  float* v1d  = F; F += DD;
  float* v2s  = F; F += DD;
  float* v2d  = F; F += DD;
  float* esS1 = F; F += NS;
  float* izS1 = F; F += NS;
  float* esS2 = F; F += NS;
  float* izS2 = F; F += NS;
  float* esP  = F; F += 128;
  float* izP  = F; F += 128;
  // f16 split workspace (all bases 16B aligned; sizes multiples of 8 halves)
  f16* H = (f16*)F;
  f16* M1h  = H; H += (size_t)1152 * DD;   // rows: 100 prox + 1024 samp + pad
  f16* M1l  = H; H += (size_t)1152 * DD;
  f16* M2h  = H; H += (size_t)NS * DD;
  f16* M2l  = H; H += (size_t)NS * DD;
  f16* Es1h = H; H += (size_t)NS * 128;
  f16* Es1l = H; H += (size_t)NS * 128;
  f16* Es2h = H; H += (size_t)NS * 128;
  f16* Es2l = H; H += (size_t)NS * 128;
  f16* Eph  = H; H += (size_t)128 * NS;
  f16* Epl  = H; H += (size_t)128 * NS;
  f16* xth  = H; H += (size_t)DD * NS;     // x^T  [512][1024]
  f16* xtl  = H; H += (size_t)DD * NS;
  f16* pth  = H; H += (size_t)DD * 128;    // prox^T [512][128] (k-pad zeroed)
  f16* ptl  = H; H += (size_t)DD * 128;
  f16* W1th = H; H += (size_t)DD * DD;     // W1^T [512][512]
  f16* W1tl = H; H += (size_t)DD * DD;
  f16* W2th = H; H += (size_t)DD * DD;
  f16* W2tl = H; H += (size_t)DD * DD;
  f16* fwth = H; H += (size_t)128 * DD;    // fcw^T [128][512] (k-pad zeroed)
  f16* fwtl = H; H += (size_t)128 * DD;
  f16* h2h  = H; H += (size_t)NS * DD;
  f16* h2l  = H; H += (size_t)NS * DD;
  f16* h1pth = H; H += (size_t)DD * 128;   // h1 proxy rows ^T [512][128]
  f16* h1ptl = H; H += (size_t)DD * 128;
  float* h2s = out + (size_t)NS * CC;      // layer-2 sample out in d_out

  dim3 blk(NTHR);
  // 1: transposes/splits of inputs + weight-side matvecs
  prep_k<<<dim3(544), blk, 0, stream>>>(x, prox, W1, W2, fcw, as1, ad1, as2, ad2,
      xth, xtl, pth, ptl, W1th, W1tl, W2th, W2tl, fwth, fwtl,
      v1s, v1d, v2s, v2d);
  // 2: layer-1 logits
  lvec_k<<<dim3(281), blk, 0, stream>>>(prox, x, PP, v1s, v1d, ls1, ld1);
  // 3: layer-1 softmax weights (samples + proxies + Ep k-pad zero-fill)
  alpha_k<<<dim3(256 + 128), blk, 0, stream>>>(ls1, ld1, Es1h, Es1l, esS1, izS1,
                                               Eph, Epl, esP, izP);
  // 4: layer-1 aggregation -> M1 (split)
  agg1_k<<<dim3(144), blk, 0, stream>>>(Es1h, Es1l, pth, ptl, Eph, Epl, xth, xtl,
                                        x, prox, esS1, izS1, esP, izP, M1h, M1l);
  // 5: h1 = relu(M1@W1 + b1)  (fp32 + split-T proxy rows)
  h1_k<<<dim3(144), blk, 0, stream>>>(M1h, M1l, W1th, W1tl, b1, h1, h1pth, h1ptl);
  // 6: layer-2 logits
  lvec_k<<<dim3(281), blk, 0, stream>>>(h1, h1, NN, v2s, v2d, ls2, ld2);
  // 7: layer-2 softmax weights (samples only; proxy branch never runs)
  alpha_k<<<dim3(256), blk, 0, stream>>>(ls2, ld2, Es2h, Es2l, esS2, izS2,
                                         Eph, Epl, esP, izP);
  // 8: layer-2 aggregation -> M2 (split)
  agg2_k<<<dim3(128), blk, 0, stream>>>(Es2h, Es2l, h1pth, h1ptl, h1,
                                        esS2, izS2, M2h, M2l);
  // 9: h2 = relu(M2@W2 + b2) -> d_out (+ split)
  h2_k<<<dim3(128), blk, 0, stream>>>(M2h, M2l, W2th, W2tl, b2, h2s, h2h, h2l);
  // 10: preds = h2 @ fcw + fcb
  fc_k<<<dim3(32), blk, 0, stream>>>(h2h, h2l, fwth, fwtl, fcb, out);
}